// Round 6
// baseline (470.887 us; speedup 1.0000x reference)
//
#include <hip/hip_runtime.h>
#include <stdint.h>

#define VOCAB 28996
#define EMBED 512
#define NROWS 8192
#define VPAD  29056  /* 227 * 128 */
#define LOG2E 1.4426950408889634f
#define WSCALE 16.0f
#define INV_WSCALE_L2E (LOG2E / 16.0f)
#define GEMM_BLOCKS (64 * 227)

typedef __attribute__((ext_vector_type(4)))  int   i32x4;
typedef __attribute__((ext_vector_type(8)))  int   i32x8;
typedef __attribute__((ext_vector_type(16))) float f32x16;

__device__ __forceinline__ void gload_lds16(const void* g, void* l) {
  __builtin_amdgcn_global_load_lds(
      (__attribute__((address_space(1))) const void*)g,
      (__attribute__((address_space(3))) void*)l, 16, 0, 0);
}

// pack 4 floats -> 4 x fp8 e4m3 (OCP, RNE, saturating) in one i32
__device__ __forceinline__ int pk_fp8x4(float a, float b, float c, float d) {
  int r = __builtin_amdgcn_cvt_pk_fp8_f32(a, b, 0, false);
  r = __builtin_amdgcn_cvt_pk_fp8_f32(c, d, r, true);
  return r;
}

// ---- fused prep: cvt W*16 -> fp8 (pad to VPAD), cvt x -> fp8, p_y, zero sg ----
// blocks [0,7264): W   (VPAD*512/8/256 = 7264)
// blocks [7264,9312): x (8192*512/8/256 = 2048)
// blocks [9312,11360): py (1 wave/row, 4 rows/block)
// blocks [11360,11392): zero sg (+ completion counter)
__global__ void __launch_bounds__(256)
prep_kernel(const float* __restrict__ x, const float* __restrict__ W,
            const float* __restrict__ b, const int* __restrict__ y,
            int* __restrict__ xb, int* __restrict__ wb,
            float* __restrict__ py, float* __restrict__ sg,
            unsigned* __restrict__ counter) {
  const int bid = blockIdx.x;
  if (bid < 7264) {                        // ---- cvt W*16 -> fp8 ----
    int i = (bid * 256 + threadIdx.x) * 8; // float index; VK multiple of 8
    const int VK = VOCAB * EMBED;
    int2 o;
    if (i < VK) {
      float4 v0 = *(const float4*)(W + i);
      float4 v1 = *(const float4*)(W + i + 4);
      o.x = pk_fp8x4(v0.x * WSCALE, v0.y * WSCALE, v0.z * WSCALE, v0.w * WSCALE);
      o.y = pk_fp8x4(v1.x * WSCALE, v1.y * WSCALE, v1.z * WSCALE, v1.w * WSCALE);
    } else { o.x = 0; o.y = 0; }
    *(int2*)(wb + i / 4) = o;
  } else if (bid < 9312) {                 // ---- cvt x -> fp8 ----
    int i = ((bid - 7264) * 256 + threadIdx.x) * 8;
    float4 v0 = *(const float4*)(x + i);
    float4 v1 = *(const float4*)(x + i + 4);
    int2 o;
    o.x = pk_fp8x4(v0.x, v0.y, v0.z, v0.w);
    o.y = pk_fp8x4(v1.x, v1.y, v1.z, v1.w);
    *(int2*)(xb + i / 4) = o;
  } else if (bid < 11360) {                // ---- py: e^{x.W[y]+b[y]}, fp32 exact ----
    const int row  = ((bid - 9312) * 256 + threadIdx.x) >> 6;
    const int lane = threadIdx.x & 63;
    const int yr = y[row];
    const float4* xr = (const float4*)(x + (size_t)row * EMBED);
    const float4* wr = (const float4*)(W + (size_t)yr * EMBED);
    float d = 0.f;
#pragma unroll
    for (int t = 0; t < 2; ++t) {
      float4 a = xr[lane * 2 + t], c = wr[lane * 2 + t];
      d += a.x * c.x + a.y * c.y + a.z * c.z + a.w * c.w;
    }
#pragma unroll
    for (int m = 1; m < 64; m <<= 1) d += __shfl_xor(d, m);
    if (lane == 0) py[row] = __expf(d + b[yr]);
  } else {                                 // ---- zero sg + counter ----
    int i = (bid - 11360) * 256 + threadIdx.x;
    sg[i] = 0.f;
    if (bid == 11360 && threadIdx.x == 0) *counter = 0u;
  }
}

// ---- fused GEMM (16*logits = x . (16W)^T, MX-fp8 32x32x64) + row-sum exp
//      + last-block finalize (loss = log(V+1) - mean(py/s)) ----
// 128x128 tile, BK=128 staged; 4 waves 2x2, each wave 64x64 = 2x2 of 32x32.
// LDS row = 128 B; 16B-chunk XOR swizzle (chunk J of row R at
// LDS[R*128 + ((J^(R&7))*16)]) — staging contiguous for global_load_lds.
// Fragment reads issue all c0-halves then all c1-halves (conflict probe).
__global__ void __launch_bounds__(256, 4)
gemm_stats_kernel(const uint8_t* __restrict__ xb, const uint8_t* __restrict__ wb,
                  const float* __restrict__ bias, float* __restrict__ sg,
                  const float* __restrict__ py, unsigned* __restrict__ counter,
                  float* __restrict__ out) {
  __shared__ uint8_t lA[128 * 128];
  __shared__ uint8_t lB[128 * 128];
  __shared__ bool amLast;

  const int tid  = threadIdx.x;
  const int lane = tid & 63;
  const int w    = tid >> 6;       // wave 0..3
  const int l31  = lane & 31;
  const int h    = lane >> 5;      // k-half for 32x32 operands
  const int kx   = lane & 7;       // swizzle key (fragment row & 7 == lane & 7)
  const int wr   = (w >> 1) * 64;  // wave row offset in tile
  const int wc   = (w & 1) * 64;   // wave col offset in tile
  const int rowBase = blockIdx.x * 128;  // x rows (grid.x = 64)
  const int colBase = blockIdx.y * 128;  // vocab cols (grid.y = 227)

  f32x16 acc[2][2];
#pragma unroll
  for (int i = 0; i < 2; ++i)
#pragma unroll
    for (int j = 0; j < 2; ++j)
#pragma unroll
      for (int r = 0; r < 16; ++r) acc[i][j][r] = 0.f;

  const int srow = lane >> 3;                    // 0..7 (row within 8-row chunk)
  const int skel = ((lane & 7) ^ srow) * 16;     // swizzled byte offset in row

  const int aBase = (wr + l31) * 128;            // ii=0 fragment row base
  const int bBase = (wc + l31) * 128;            // jj=0 fragment row base

  for (int kt = 0; kt < 4; ++kt) {
    const int k0 = kt * 128;                     // byte offset in 512B row
#pragma unroll
    for (int t = 0; t < 4; ++t) {
      const int c = w * 4 + t;                   // chunk 0..15 (8 rows each)
      const int r = c * 8 + srow;                // tile row 0..127
      gload_lds16(xb + (size_t)(rowBase + r) * EMBED + k0 + skel, &lA[c * 1024]);
      gload_lds16(wb + (size_t)(colBase + r) * EMBED + k0 + skel, &lB[c * 1024]);
    }
    __syncthreads();
#pragma unroll
    for (int kk = 0; kk < 2; ++kk) {
      // lane's 32 k-bytes: chunks J0, J0+1 where J0 = kk*4 + h*2 (even)
      const int c0 = ((kk * 4 + h * 2) ^ kx) << 4;
      const int c1 = c0 ^ 16;                    // ((J0|1)^kx)*16
      i32x4 blo[2], bhi[2], alo[2], ahi[2];
#pragma unroll
      for (int jj = 0; jj < 2; ++jj) blo[jj] = *(const i32x4*)&lB[bBase + jj * 4096 + c0];
#pragma unroll
      for (int ii = 0; ii < 2; ++ii) alo[ii] = *(const i32x4*)&lA[aBase + ii * 4096 + c0];
#pragma unroll
      for (int jj = 0; jj < 2; ++jj) bhi[jj] = *(const i32x4*)&lB[bBase + jj * 4096 + c1];
#pragma unroll
      for (int ii = 0; ii < 2; ++ii) ahi[ii] = *(const i32x4*)&lA[aBase + ii * 4096 + c1];
#pragma unroll
      for (int ii = 0; ii < 2; ++ii) {
        i32x8 af = __builtin_shufflevector(alo[ii], ahi[ii], 0, 1, 2, 3, 4, 5, 6, 7);
#pragma unroll
        for (int jj = 0; jj < 2; ++jj) {
          i32x8 bq = __builtin_shufflevector(blo[jj], bhi[jj], 0, 1, 2, 3, 4, 5, 6, 7);
          acc[ii][jj] = __builtin_amdgcn_mfma_scale_f32_32x32x64_f8f6f4(
              af, bq, acc[ii][jj], 0, 0, 0, 0x7F7F7F7F, 0, 0x7F7F7F7F);
        }
      }
    }
    __syncthreads();
  }

  // ---- epilogue: s_row += sum_j exp(acc/16 + bias) ----
  // 32x32 C/D layout (m74/m101): col = lane&31, row = (reg&3)+8*(reg>>2)+4*h
  float bvl[2];
#pragma unroll
  for (int jj = 0; jj < 2; ++jj) {
    const int col = colBase + wc + jj * 32 + l31;
    bvl[jj] = (col < VOCAB) ? bias[col] * LOG2E : -1e30f;
  }

  float sp[32];  // v = ii*16 + reg
#pragma unroll
  for (int ii = 0; ii < 2; ++ii)
#pragma unroll
    for (int r = 0; r < 16; ++r)
      sp[ii * 16 + r] = exp2f(fmaf(acc[ii][0][r], INV_WSCALE_L2E, bvl[0])) +
                        exp2f(fmaf(acc[ii][1][r], INV_WSCALE_L2E, bvl[1]));

  // stacking reduction over the 32 cols (xor 1..16 stays within the h-half);
  // ends with lane holding the full col-sum for value index v == (lane&31).
  float t1[16];
#pragma unroll
  for (int u = 0; u < 16; ++u) {
    float a = sp[2 * u]     + __shfl_xor(sp[2 * u],     1);
    float b = sp[2 * u + 1] + __shfl_xor(sp[2 * u + 1], 1);
    t1[u] = (l31 & 1) ? b : a;
  }
  float t2[8];
#pragma unroll
  for (int u = 0; u < 8; ++u) {
    float a = t1[2 * u]     + __shfl_xor(t1[2 * u],     2);
    float b = t1[2 * u + 1] + __shfl_xor(t1[2 * u + 1], 2);
    t2[u] = (l31 & 2) ? b : a;
  }
  float t3[4];
#pragma unroll
  for (int u = 0; u < 4; ++u) {
    float a = t2[2 * u]     + __shfl_xor(t2[2 * u],     4);
    float b = t2[2 * u + 1] + __shfl_xor(t2[2 * u + 1], 4);
    t3[u] = (l31 & 4) ? b : a;
  }
  float t4[2];
#pragma unroll
  for (int u = 0; u < 2; ++u) {
    float a = t3[2 * u]     + __shfl_xor(t3[2 * u],     8);
    float b = t3[2 * u + 1] + __shfl_xor(t3[2 * u + 1], 8);
    t4[u] = (l31 & 8) ? b : a;
  }
  {
    float a = t4[0] + __shfl_xor(t4[0], 16);
    float b = t4[1] + __shfl_xor(t4[1], 16);
    float ssum = (l31 & 16) ? b : a;
    const int v = l31;                 // ii = v>>4, reg = v&15
    const int row = rowBase + wr + (v >> 4) * 32 + (v & 3) + 8 * ((v & 15) >> 2) + 4 * h;
    atomicAdd(&sg[row], ssum);
  }

  // ---- last-block finalize: loss = log(V+1) - mean(py/s) ----
  if (tid == 0) {
    unsigned old = __hip_atomic_fetch_add(counter, 1u, __ATOMIC_ACQ_REL,
                                          __HIP_MEMORY_SCOPE_AGENT);
    amLast = (old == (unsigned)(GEMM_BLOCKS - 1));
  }
  __syncthreads();
  if (amLast) {
    float a = 0.f;
    for (int i = tid; i < NROWS; i += 256) {
      // agent-scope load: sg was written by device atomics (L2 coherence point)
      float s = __hip_atomic_load(&sg[i], __ATOMIC_RELAXED, __HIP_MEMORY_SCOPE_AGENT);
      a += py[i] / s;
    }
    float* red = (float*)lA;   // reuse LDS
    red[tid] = a;
    __syncthreads();
    for (int st = 128; st > 0; st >>= 1) {
      if (tid < st) red[tid] += red[tid + st];
      __syncthreads();
    }
    if (tid == 0)
      out[0] = logf((float)(VOCAB + 1)) - red[0] * (1.f / (float)NROWS);
  }
}

extern "C" void kernel_launch(void* const* d_in, const int* in_sizes, int n_in,
                              void* d_out, int out_size, void* d_ws, size_t ws_size,
                              hipStream_t stream) {
  const float* x = (const float*)d_in[0];
  const int*   y = (const int*)d_in[1];
  const float* W = (const float*)d_in[2];
  const float* b = (const float*)d_in[3];

  char* ws = (char*)d_ws;
  uint8_t*  xb = (uint8_t*)ws;                            // 4,194,304 B
  uint8_t*  wb = (uint8_t*)(ws + 4194304);                // 14,876,672 B
  float*    sg = (float*)(ws + 4194304 + 14876672);       // 32 KiB
  float*    py = sg + NROWS;                              // 32 KiB
  unsigned* counter = (unsigned*)(py + NROWS);            // 4 B

  prep_kernel<<<11392, 256, 0, stream>>>(x, W, b, y, (int*)xb, (int*)wb, py, sg, counter);
  gemm_stats_kernel<<<dim3(64, 227), 256, 0, stream>>>(xb, wb, b, sg, py, counter,
                                                       (float*)d_out);
}

// Round 7
// 311.514 us; speedup vs baseline: 1.5116x; 1.5116x over previous
//
#include <hip/hip_runtime.h>
#include <stdint.h>

#define VOCAB 28996
#define EMBED 512
#define NROWS 8192
#define VPAD  29056  /* 227 * 128 */
#define LOG2E 1.4426950408889634f
#define WSCALE 16.0f
#define INV_WSCALE_L2E (LOG2E / 16.0f)

typedef __attribute__((ext_vector_type(4)))  int   i32x4;
typedef __attribute__((ext_vector_type(8)))  int   i32x8;
typedef __attribute__((ext_vector_type(16))) float f32x16;

__device__ __forceinline__ void gload_lds16(const void* g, void* l) {
  __builtin_amdgcn_global_load_lds(
      (__attribute__((address_space(1))) const void*)g,
      (__attribute__((address_space(3))) void*)l, 16, 0, 0);
}

// pack 4 floats -> 4 x fp8 e4m3 (OCP, RNE, saturating) in one i32
__device__ __forceinline__ int pk_fp8x4(float a, float b, float c, float d) {
  int r = __builtin_amdgcn_cvt_pk_fp8_f32(a, b, 0, false);
  r = __builtin_amdgcn_cvt_pk_fp8_f32(c, d, r, true);
  return r;
}

// ---- fused prep: cvt W*16 -> fp8 (pad to VPAD), cvt x -> fp8, p_y, zero sg ----
// blocks [0,7264): W   (VPAD*512/8/256 = 7264)
// blocks [7264,9312): x (8192*512/8/256 = 2048)
// blocks [9312,11360): py (1 wave/row, 4 rows/block)
// blocks [11360,11392): zero sg
__global__ void __launch_bounds__(256)
prep_kernel(const float* __restrict__ x, const float* __restrict__ W,
            const float* __restrict__ b, const int* __restrict__ y,
            int* __restrict__ xb, int* __restrict__ wb,
            float* __restrict__ py, float* __restrict__ sg) {
  const int bid = blockIdx.x;
  if (bid < 7264) {                        // ---- cvt W*16 -> fp8 ----
    int i = (bid * 256 + threadIdx.x) * 8; // float index; VK multiple of 8
    const int VK = VOCAB * EMBED;
    int2 o;
    if (i < VK) {
      float4 v0 = *(const float4*)(W + i);
      float4 v1 = *(const float4*)(W + i + 4);
      o.x = pk_fp8x4(v0.x * WSCALE, v0.y * WSCALE, v0.z * WSCALE, v0.w * WSCALE);
      o.y = pk_fp8x4(v1.x * WSCALE, v1.y * WSCALE, v1.z * WSCALE, v1.w * WSCALE);
    } else { o.x = 0; o.y = 0; }
    *(int2*)(wb + i / 4) = o;
  } else if (bid < 9312) {                 // ---- cvt x -> fp8 ----
    int i = ((bid - 7264) * 256 + threadIdx.x) * 8;
    float4 v0 = *(const float4*)(x + i);
    float4 v1 = *(const float4*)(x + i + 4);
    int2 o;
    o.x = pk_fp8x4(v0.x, v0.y, v0.z, v0.w);
    o.y = pk_fp8x4(v1.x, v1.y, v1.z, v1.w);
    *(int2*)(xb + i / 4) = o;
  } else if (bid < 11360) {                // ---- py: e^{x.W[y]+b[y]}, fp32 exact ----
    const int row  = ((bid - 9312) * 256 + threadIdx.x) >> 6;
    const int lane = threadIdx.x & 63;
    const int yr = y[row];
    const float4* xr = (const float4*)(x + (size_t)row * EMBED);
    const float4* wr = (const float4*)(W + (size_t)yr * EMBED);
    float d = 0.f;
#pragma unroll
    for (int t = 0; t < 2; ++t) {
      float4 a = xr[lane * 2 + t], c = wr[lane * 2 + t];
      d += a.x * c.x + a.y * c.y + a.z * c.z + a.w * c.w;
    }
#pragma unroll
    for (int m = 1; m < 64; m <<= 1) d += __shfl_xor(d, m);
    if (lane == 0) py[row] = __expf(d + b[yr]);
  } else {                                 // ---- zero sg ----
    int i = (bid - 11360) * 256 + threadIdx.x;
    sg[i] = 0.f;
  }
}

// ---- fused GEMM (16*logits = x . (16W)^T, MX-fp8 32x32x64) + row-sum exp ----
// 128x128 tile, BK=128; 4 waves 2x2, each wave 64x64 = 2x2 of 32x32.
// DOUBLE-BUFFERED LDS pipeline: stage(kt+1) is issued BEFORE compute(kt) with
// no barrier in between, so the compiler's vmcnt(0)-before-s_barrier drain
// happens after the loads had the whole compute phase to land (drain ~ free).
// Only the prologue stage(0) drain is exposed. 5 barriers vs 8, 64 KB LDS
// (2 blocks/CU). 16B-chunk XOR swizzle as before (conflict-free staging,
// fragment reads spread across banks).
__global__ void __launch_bounds__(256, 4)
gemm_stats_kernel(const uint8_t* __restrict__ xb, const uint8_t* __restrict__ wb,
                  const float* __restrict__ bias, float* __restrict__ sg) {
  __shared__ uint8_t lds[4][16384];   // [0]=A0 [1]=B0 [2]=A1 [3]=B1

  const int tid  = threadIdx.x;
  const int lane = tid & 63;
  const int w    = tid >> 6;       // wave 0..3
  const int l31  = lane & 31;
  const int h    = lane >> 5;      // k-half for 32x32 operands
  const int kx   = lane & 7;       // swizzle key (fragment row & 7 == lane & 7)
  const int wr   = (w >> 1) * 64;  // wave row offset in tile
  const int wc   = (w & 1) * 64;   // wave col offset in tile
  const int rowBase = blockIdx.x * 128;  // x rows (grid.x = 64)
  const int colBase = blockIdx.y * 128;  // vocab cols (grid.y = 227)

  f32x16 acc[2][2];
#pragma unroll
  for (int i = 0; i < 2; ++i)
#pragma unroll
    for (int j = 0; j < 2; ++j)
#pragma unroll
      for (int r = 0; r < 16; ++r) acc[i][j][r] = 0.f;

  const int srow = lane >> 3;                    // 0..7 (row within 8-row chunk)
  const int skel = ((lane & 7) ^ srow) * 16;     // swizzled byte offset in row

  const int aBase = (wr + l31) * 128;            // ii=0 fragment row base
  const int bBase = (wc + l31) * 128;            // jj=0 fragment row base

  // stage K-tile kt into (bufA, bufB)
  auto stage = [&](int kt, uint8_t* bufA, uint8_t* bufB) {
    const int k0 = kt * 128;
#pragma unroll
    for (int t = 0; t < 4; ++t) {
      const int c = w * 4 + t;                   // chunk 0..15 (8 rows each)
      const int r = c * 8 + srow;                // tile row 0..127
      gload_lds16(xb + (size_t)(rowBase + r) * EMBED + k0 + skel, &bufA[c * 1024]);
      gload_lds16(wb + (size_t)(colBase + r) * EMBED + k0 + skel, &bufB[c * 1024]);
    }
  };

  // compute one K-tile from (bufA, bufB)  — R5-proven inner structure
  auto compute = [&](const uint8_t* bufA, const uint8_t* bufB) {
#pragma unroll
    for (int kk = 0; kk < 2; ++kk) {
      const int c0 = ((kk * 4 + h * 2) ^ kx) << 4;
      const int c1 = c0 ^ 16;
      i32x8 bq[2];
#pragma unroll
      for (int jj = 0; jj < 2; ++jj) {
        const int base = bBase + jj * 4096;
        i32x4 lo = *(const i32x4*)&bufB[base + c0];
        i32x4 hi = *(const i32x4*)&bufB[base + c1];
        bq[jj] = __builtin_shufflevector(lo, hi, 0, 1, 2, 3, 4, 5, 6, 7);
      }
#pragma unroll
      for (int ii = 0; ii < 2; ++ii) {
        const int base = aBase + ii * 4096;
        i32x4 lo = *(const i32x4*)&bufA[base + c0];
        i32x4 hi = *(const i32x4*)&bufA[base + c1];
        i32x8 af = __builtin_shufflevector(lo, hi, 0, 1, 2, 3, 4, 5, 6, 7);
        acc[ii][0] = __builtin_amdgcn_mfma_scale_f32_32x32x64_f8f6f4(
            af, bq[0], acc[ii][0], 0, 0, 0, 0x7F7F7F7F, 0, 0x7F7F7F7F);
        acc[ii][1] = __builtin_amdgcn_mfma_scale_f32_32x32x64_f8f6f4(
            af, bq[1], acc[ii][1], 0, 0, 0, 0x7F7F7F7F, 0, 0x7F7F7F7F);
      }
    }
  };

  stage(0, lds[0], lds[1]);
  __syncthreads();                 // exposed drain (prologue only)
  stage(1, lds[2], lds[3]);        // in flight during compute(0)
  compute(lds[0], lds[1]);
  __syncthreads();                 // drains stage(1) — already landed
  stage(2, lds[0], lds[1]);        // buf0 free: compute(0) done before barrier
  compute(lds[2], lds[3]);
  __syncthreads();                 // drains stage(2)
  stage(3, lds[2], lds[3]);
  compute(lds[0], lds[1]);
  __syncthreads();                 // drains stage(3)
  compute(lds[2], lds[3]);
  // no trailing barrier: epilogue uses no LDS

  // ---- epilogue: s_row += sum_j exp(acc/16 + bias) ----
  // 32x32 C/D layout (m74/m101): col = lane&31, row = (reg&3)+8*(reg>>2)+4*h
  float bvl[2];
#pragma unroll
  for (int jj = 0; jj < 2; ++jj) {
    const int col = colBase + wc + jj * 32 + l31;
    bvl[jj] = (col < VOCAB) ? bias[col] * LOG2E : -1e30f;
  }

  float sp[32];  // v = ii*16 + reg
#pragma unroll
  for (int ii = 0; ii < 2; ++ii)
#pragma unroll
    for (int r = 0; r < 16; ++r)
      sp[ii * 16 + r] = exp2f(fmaf(acc[ii][0][r], INV_WSCALE_L2E, bvl[0])) +
                        exp2f(fmaf(acc[ii][1][r], INV_WSCALE_L2E, bvl[1]));

  // stacking reduction over the 32 cols (xor 1..16 stays within the h-half);
  // ends with lane holding the full col-sum for value index v == (lane&31).
  float t1[16];
#pragma unroll
  for (int u = 0; u < 16; ++u) {
    float a = sp[2 * u]     + __shfl_xor(sp[2 * u],     1);
    float b = sp[2 * u + 1] + __shfl_xor(sp[2 * u + 1], 1);
    t1[u] = (l31 & 1) ? b : a;
  }
  float t2[8];
#pragma unroll
  for (int u = 0; u < 8; ++u) {
    float a = t1[2 * u]     + __shfl_xor(t1[2 * u],     2);
    float b = t1[2 * u + 1] + __shfl_xor(t1[2 * u + 1], 2);
    t2[u] = (l31 & 2) ? b : a;
  }
  float t3[4];
#pragma unroll
  for (int u = 0; u < 4; ++u) {
    float a = t2[2 * u]     + __shfl_xor(t2[2 * u],     4);
    float b = t2[2 * u + 1] + __shfl_xor(t2[2 * u + 1], 4);
    t3[u] = (l31 & 4) ? b : a;
  }
  float t4[2];
#pragma unroll
  for (int u = 0; u < 2; ++u) {
    float a = t3[2 * u]     + __shfl_xor(t3[2 * u],     8);
    float b = t3[2 * u + 1] + __shfl_xor(t3[2 * u + 1], 8);
    t4[u] = (l31 & 8) ? b : a;
  }
  {
    float a = t4[0] + __shfl_xor(t4[0], 16);
    float b = t4[1] + __shfl_xor(t4[1], 16);
    float ssum = (l31 & 16) ? b : a;
    const int v = l31;                 // ii = v>>4, reg = v&15
    const int row = rowBase + wr + (v >> 4) * 32 + (v & 3) + 8 * ((v & 15) >> 2) + 4 * h;
    atomicAdd(&sg[row], ssum);
  }
}

// ---- final: loss = log(V+1) - mean(py/s)  (q-term ~7e-10, dropped) ----
__global__ void finalize_kernel(const float* __restrict__ sg, const float* __restrict__ py,
                                float* __restrict__ out) {
  __shared__ float red[256];
  float a = 0.f;
  for (int i = threadIdx.x; i < NROWS; i += 256)
    a += py[i] / sg[i];
  red[threadIdx.x] = a;
  __syncthreads();
  for (int st = 128; st > 0; st >>= 1) {
    if (threadIdx.x < st) red[threadIdx.x] += red[threadIdx.x + st];
    __syncthreads();
  }
  if (threadIdx.x == 0)
    out[0] = logf((float)(VOCAB + 1)) - red[0] * (1.f / (float)NROWS);
}

extern "C" void kernel_launch(void* const* d_in, const int* in_sizes, int n_in,
                              void* d_out, int out_size, void* d_ws, size_t ws_size,
                              hipStream_t stream) {
  const float* x = (const float*)d_in[0];
  const int*   y = (const int*)d_in[1];
  const float* W = (const float*)d_in[2];
  const float* b = (const float*)d_in[3];

  char* ws = (char*)d_ws;
  uint8_t* xb = (uint8_t*)ws;                             // 4,194,304 B
  uint8_t* wb = (uint8_t*)(ws + 4194304);                 // 14,876,672 B
  float*   sg = (float*)(ws + 4194304 + 14876672);        // 32 KiB
  float*   py = sg + NROWS;                               // 32 KiB

  prep_kernel<<<11392, 256, 0, stream>>>(x, W, b, y, (int*)xb, (int*)wb, py, sg);
  gemm_stats_kernel<<<dim3(64, 227), 256, 0, stream>>>(xb, wb, b, sg);
  finalize_kernel<<<1, 256, 0, stream>>>(sg, py, (float*)d_out);
}

// Round 8
// 281.701 us; speedup vs baseline: 1.6716x; 1.1058x over previous
//
#include <hip/hip_runtime.h>
#include <stdint.h>

#define VOCAB 28996
#define EMBED 512
#define NROWS 8192
#define VPAD  29056  /* 227 * 128 */
#define LOG2E 1.4426950408889634f
#define WSCALE 16.0f
#define INV_WSCALE_L2E (LOG2E / 16.0f)

typedef __attribute__((ext_vector_type(4)))  int   i32x4;
typedef __attribute__((ext_vector_type(8)))  int   i32x8;
typedef __attribute__((ext_vector_type(16))) float f32x16;

// pack 4 floats -> 4 x fp8 e4m3 (OCP, RNE, saturating) in one i32
__device__ __forceinline__ int pk_fp8x4(float a, float b, float c, float d) {
  int r = __builtin_amdgcn_cvt_pk_fp8_f32(a, b, 0, false);
  r = __builtin_amdgcn_cvt_pk_fp8_f32(c, d, r, true);
  return r;
}

// Fragment-major tiled layout: tile T[g][s] (g = 32-row group, s = 64-k step)
// is 2048 B; lane index lam = h*32 + (row&31) holds row's k-bytes
// [s*64 + h*32, +32) at T + lam*32. A wave's fragment load is then one
// contiguous 2 KB burst (2x dwordx4 per lane) — no LDS needed in the GEMM.
__device__ __forceinline__ size_t tile_dst(int r, int o) {
  // r = row, o = k-offset in [0,512); returns byte offset of the 8-byte group
  return (size_t)((r >> 5) * 8 + (o >> 6)) * 2048 +
         (((o >> 5) & 1) * 32 + (r & 31)) * 32 + (o & 31);
}

// ---- fused prep: W*16 -> fp8 tiles (pad to VPAD), x -> fp8 tiles, p_y, sg=0 ----
// blocks [0,7264): W   (VPAD*512/8/256 = 7264)
// blocks [7264,9312): x (8192*512/8/256 = 2048)
// blocks [9312,11360): py (1 wave/row, 4 rows/block)
// blocks [11360,11392): zero sg
__global__ void __launch_bounds__(256)
prep_kernel(const float* __restrict__ x, const float* __restrict__ W,
            const float* __restrict__ b, const int* __restrict__ y,
            uint8_t* __restrict__ xT, uint8_t* __restrict__ wT,
            float* __restrict__ py, float* __restrict__ sg) {
  const int bid = blockIdx.x;
  if (bid < 7264) {                        // ---- cvt W*16 -> fp8 tiles ----
    int i = (bid * 256 + threadIdx.x) * 8; // float index in [0, VPAD*512)
    const int VK = VOCAB * EMBED;
    int2 o;
    if (i < VK) {
      float4 v0 = *(const float4*)(W + i);
      float4 v1 = *(const float4*)(W + i + 4);
      o.x = pk_fp8x4(v0.x * WSCALE, v0.y * WSCALE, v0.z * WSCALE, v0.w * WSCALE);
      o.y = pk_fp8x4(v1.x * WSCALE, v1.y * WSCALE, v1.z * WSCALE, v1.w * WSCALE);
    } else { o.x = 0; o.y = 0; }
    *(int2*)(wT + tile_dst(i >> 9, i & 511)) = o;
  } else if (bid < 9312) {                 // ---- cvt x -> fp8 tiles ----
    int i = ((bid - 7264) * 256 + threadIdx.x) * 8;
    float4 v0 = *(const float4*)(x + i);
    float4 v1 = *(const float4*)(x + i + 4);
    int2 o;
    o.x = pk_fp8x4(v0.x, v0.y, v0.z, v0.w);
    o.y = pk_fp8x4(v1.x, v1.y, v1.z, v1.w);
    *(int2*)(xT + tile_dst(i >> 9, i & 511)) = o;
  } else if (bid < 11360) {                // ---- py: e^{x.W[y]+b[y]}, fp32 exact ----
    const int row  = ((bid - 9312) * 256 + threadIdx.x) >> 6;
    const int lane = threadIdx.x & 63;
    const int yr = y[row];
    const float4* xr = (const float4*)(x + (size_t)row * EMBED);
    const float4* wr = (const float4*)(W + (size_t)yr * EMBED);
    float d = 0.f;
#pragma unroll
    for (int t = 0; t < 2; ++t) {
      float4 a = xr[lane * 2 + t], c = wr[lane * 2 + t];
      d += a.x * c.x + a.y * c.y + a.z * c.z + a.w * c.w;
    }
#pragma unroll
    for (int m = 1; m < 64; m <<= 1) d += __shfl_xor(d, m);
    if (lane == 0) py[row] = __expf(d + b[yr]);
  } else {                                 // ---- zero sg ----
    int i = (bid - 11360) * 256 + threadIdx.x;
    sg[i] = 0.f;
  }
}

// ---- fused GEMM (16*logits = x . (16W)^T, MX-fp8 32x32x64) + row-sum exp ----
// NO LDS, NO barriers: A/B fragments load directly global->VGPR from the
// fragment-major tiles (one coalesced 2 KB burst per fragment). 128x128 block
// tile via 4 independent waves (2x2, each 64x64 = 2x2 of 32x32). The K-loop
// (8 steps of k=64) is a pure load->MFMA stream the compiler can pipeline
// with fine-grained vmcnt — no vmcnt(0)-before-barrier drain exists.
__global__ void __launch_bounds__(256, 3)
gemm_stats_kernel(const uint8_t* __restrict__ xT, const uint8_t* __restrict__ wT,
                  const float* __restrict__ bias, float* __restrict__ sg) {
  const int tid  = threadIdx.x;
  const int lane = tid & 63;
  const int w    = tid >> 6;       // wave 0..3
  const int l31  = lane & 31;
  const int h    = lane >> 5;      // k-half within a 64-k step
  const int wr   = (w >> 1) * 64;  // wave row offset in tile
  const int wc   = (w & 1) * 64;   // wave col offset in tile
  const int rowBase = blockIdx.x * 128;  // x rows (grid.x = 64, fast dim)
  const int colBase = blockIdx.y * 128;  // vocab cols (grid.y = 227)

  // tile-group bases: ag for rows rowBase+wr+{0,32}, bg for cols colBase+wc+{0,32}
  const uint8_t* aT = xT + ((size_t)(((rowBase + wr) >> 5) * 8)) * 2048 + lane * 32;
  const uint8_t* bT = wT + ((size_t)(((colBase + wc) >> 5) * 8)) * 2048 + lane * 32;

  f32x16 acc[2][2];
#pragma unroll
  for (int i = 0; i < 2; ++i)
#pragma unroll
    for (int j = 0; j < 2; ++j)
#pragma unroll
      for (int r = 0; r < 16; ++r) acc[i][j][r] = 0.f;

#pragma unroll
  for (int s = 0; s < 8; ++s) {
    const int offs = s * 2048;
    i32x8 af[2], bq[2];
#pragma unroll
    for (int ii = 0; ii < 2; ++ii) {
      i32x4 lo = *(const i32x4*)(aT + ii * 16384 + offs);
      i32x4 hi = *(const i32x4*)(aT + ii * 16384 + offs + 16);
      af[ii] = __builtin_shufflevector(lo, hi, 0, 1, 2, 3, 4, 5, 6, 7);
    }
#pragma unroll
    for (int jj = 0; jj < 2; ++jj) {
      i32x4 lo = *(const i32x4*)(bT + jj * 16384 + offs);
      i32x4 hi = *(const i32x4*)(bT + jj * 16384 + offs + 16);
      bq[jj] = __builtin_shufflevector(lo, hi, 0, 1, 2, 3, 4, 5, 6, 7);
    }
#pragma unroll
    for (int ii = 0; ii < 2; ++ii)
#pragma unroll
      for (int jj = 0; jj < 2; ++jj)
        acc[ii][jj] = __builtin_amdgcn_mfma_scale_f32_32x32x64_f8f6f4(
            af[ii], bq[jj], acc[ii][jj], 0, 0, 0, 0x7F7F7F7F, 0, 0x7F7F7F7F);
  }

  // ---- epilogue: s_row += sum_j exp(acc/16 + bias) ----
  // 32x32 C/D layout (m74/m101): col = lane&31, row = (reg&3)+8*(reg>>2)+4*h
  float bvl[2];
#pragma unroll
  for (int jj = 0; jj < 2; ++jj) {
    const int col = colBase + wc + jj * 32 + l31;
    bvl[jj] = (col < VOCAB) ? bias[col] * LOG2E : -1e30f;
  }

  float sp[32];  // v = ii*16 + reg
#pragma unroll
  for (int ii = 0; ii < 2; ++ii)
#pragma unroll
    for (int r = 0; r < 16; ++r)
      sp[ii * 16 + r] = exp2f(fmaf(acc[ii][0][r], INV_WSCALE_L2E, bvl[0])) +
                        exp2f(fmaf(acc[ii][1][r], INV_WSCALE_L2E, bvl[1]));

  // stacking reduction over the 32 cols (xor 1..16 stays within the h-half);
  // ends with lane holding the full col-sum for value index v == (lane&31).
  float t1[16];
#pragma unroll
  for (int u = 0; u < 16; ++u) {
    float a = sp[2 * u]     + __shfl_xor(sp[2 * u],     1);
    float b = sp[2 * u + 1] + __shfl_xor(sp[2 * u + 1], 1);
    t1[u] = (l31 & 1) ? b : a;
  }
  float t2[8];
#pragma unroll
  for (int u = 0; u < 8; ++u) {
    float a = t1[2 * u]     + __shfl_xor(t1[2 * u],     2);
    float b = t1[2 * u + 1] + __shfl_xor(t1[2 * u + 1], 2);
    t2[u] = (l31 & 2) ? b : a;
  }
  float t3[4];
#pragma unroll
  for (int u = 0; u < 4; ++u) {
    float a = t2[2 * u]     + __shfl_xor(t2[2 * u],     4);
    float b = t2[2 * u + 1] + __shfl_xor(t2[2 * u + 1], 4);
    t3[u] = (l31 & 4) ? b : a;
  }
  float t4[2];
#pragma unroll
  for (int u = 0; u < 2; ++u) {
    float a = t3[2 * u]     + __shfl_xor(t3[2 * u],     8);
    float b = t3[2 * u + 1] + __shfl_xor(t3[2 * u + 1], 8);
    t4[u] = (l31 & 8) ? b : a;
  }
  {
    float a = t4[0] + __shfl_xor(t4[0], 16);
    float b = t4[1] + __shfl_xor(t4[1], 16);
    float ssum = (l31 & 16) ? b : a;
    const int v = l31;                 // ii = v>>4, reg = v&15
    const int row = rowBase + wr + (v >> 4) * 32 + (v & 3) + 8 * ((v & 15) >> 2) + 4 * h;
    atomicAdd(&sg[row], ssum);
  }
}

// ---- final: loss = log(V+1) - mean(py/s)  (q-term ~7e-10, dropped) ----
__global__ void finalize_kernel(const float* __restrict__ sg, const float* __restrict__ py,
                                float* __restrict__ out) {
  __shared__ float red[256];
  float a = 0.f;
  for (int i = threadIdx.x; i < NROWS; i += 256)
    a += py[i] / sg[i];
  red[threadIdx.x] = a;
  __syncthreads();
  for (int st = 128; st > 0; st >>= 1) {
    if (threadIdx.x < st) red[threadIdx.x] += red[threadIdx.x + st];
    __syncthreads();
  }
  if (threadIdx.x == 0)
    out[0] = logf((float)(VOCAB + 1)) - red[0] * (1.f / (float)NROWS);
}

extern "C" void kernel_launch(void* const* d_in, const int* in_sizes, int n_in,
                              void* d_out, int out_size, void* d_ws, size_t ws_size,
                              hipStream_t stream) {
  const float* x = (const float*)d_in[0];
  const int*   y = (const int*)d_in[1];
  const float* W = (const float*)d_in[2];
  const float* b = (const float*)d_in[3];

  char* ws = (char*)d_ws;
  uint8_t* xT = (uint8_t*)ws;                             // 4,194,304 B
  uint8_t* wT = (uint8_t*)(ws + 4194304);                 // 14,876,672 B
  float*   sg = (float*)(ws + 4194304 + 14876672);        // 32 KiB
  float*   py = sg + NROWS;                               // 32 KiB

  prep_kernel<<<11392, 256, 0, stream>>>(x, W, b, y, xT, wT, py, sg);
  gemm_stats_kernel<<<dim3(64, 227), 256, 0, stream>>>(xT, wT, b, sg);
  finalize_kernel<<<1, 256, 0, stream>>>(sg, py, (float*)d_out);
}